// Round 1
// baseline (1238.201 us; speedup 1.0000x reference)
//
#include <hip/hip_runtime.h>
#include <hip/hip_bf16.h>

#define N_SRC  200000
#define N_MIDN 40000
#define N_DSTN 8000
#define RREL   4
#define E1N    1000000
#define E2N    200000
#define IN_F   256
#define HID_F  128
#define OUT_F  128
#define CAP    96   // ELL capacity; mean degree 25, P(overflow) ~ 1e-18

typedef __attribute__((ext_vector_type(8))) short bf16x8;
typedef __attribute__((ext_vector_type(4))) float f32x4;
typedef __attribute__((ext_vector_type(4))) unsigned short u16x4;

__device__ __forceinline__ unsigned short f2bf(float f) {
    unsigned int u = __float_as_uint(f);
    u = (u + 0x7FFFu + ((u >> 16) & 1u)) >> 16;   // RNE
    return (unsigned short)u;
}

// ---------------------------------------------------------------------------
// ELL build: per edge, slot = atomicAdd(cnt[r][dst]); ell[r][dst][slot] = src
// ---------------------------------------------------------------------------
__global__ __launch_bounds__(256) void fill_kernel(
    const int* __restrict__ src, const int* __restrict__ dst,
    int* __restrict__ cnt, int* __restrict__ ell,
    int epr, int ndst)
{
    int i = blockIdx.x * 256 + threadIdx.x;
    if (i >= RREL * epr) return;
    int r = i / epr;                 // const-div -> magic mul
    int s = src[i];                  // flat [R][E]
    int d = dst[i];
    int node = r * ndst + d;
    int slot = atomicAdd(&cnt[node], 1);
    if (slot < CAP) ell[node * CAP + slot] = s;
}

// ---------------------------------------------------------------------------
// GEMM: A [M][K] (fp32 or bf16) x W[r] [K][128] -> Mout [M][R*128] (bf16)
// block 256 = 4 waves; tile 128x128, full K resident in LDS; 16x16x32 MFMA
// grid: (R, ceil(M/128))
// ---------------------------------------------------------------------------
template<int K, bool IN_BF16>
__global__ __launch_bounds__(256) void gemm_kernel(
    const void* __restrict__ Ain, const float* __restrict__ W,
    unsigned short* __restrict__ Mout, int M)
{
    constexpr int KP = K + 8;                     // +16B pad: kill LDS bank conflicts
    __shared__ unsigned short As[128 * KP];       // A tile, bf16
    __shared__ unsigned short Ws[128 * KP];       // W^T tile: [n][k], bf16

    const int r   = blockIdx.x;
    const int m0  = blockIdx.y * 128;
    const int tid = threadIdx.x;

    // stage A (vectorized 4-wide, convert fp32->bf16 if needed)
    for (int i = tid; i < 128 * (K / 4); i += 256) {
        int row = i / (K / 4);
        int c4  = (i - row * (K / 4)) * 4;
        int grow = m0 + row; if (grow >= M) grow = M - 1;   // clamp (guarded at store)
        u16x4 o;
        if constexpr (IN_BF16) {
            const unsigned short* A = (const unsigned short*)Ain;
            o = *(const u16x4*)&A[grow * K + c4];
        } else {
            const float* A = (const float*)Ain;
            float4 v = *(const float4*)&A[grow * K + c4];
            o.x = f2bf(v.x); o.y = f2bf(v.y); o.z = f2bf(v.z); o.w = f2bf(v.w);
        }
        *(u16x4*)&As[row * KP + c4] = o;
    }
    // stage W transposed: Ws[n][k] = W[r][k][n]
    for (int i = tid; i < K * 128; i += 256) {
        int k = i >> 7;
        int n = i & 127;
        Ws[n * KP + k] = f2bf(W[(r * K + k) * 128 + n]);
    }
    __syncthreads();

    const int lane = tid & 63;
    const int wave = tid >> 6;
    const int wm = (wave & 1) * 64;
    const int wn = (wave >> 1) * 64;
    const int lr = lane & 15;        // A row / B col within fragment
    const int kg = lane >> 4;        // k-group: 8 contiguous k per lane

    f32x4 acc[4][4] = {};
    for (int kk = 0; kk < K; kk += 32) {
        bf16x8 af[4], bv[4];
        #pragma unroll
        for (int mi = 0; mi < 4; ++mi)
            af[mi] = *(const bf16x8*)&As[(wm + mi * 16 + lr) * KP + kk + kg * 8];
        #pragma unroll
        for (int ni = 0; ni < 4; ++ni)
            bv[ni] = *(const bf16x8*)&Ws[(wn + ni * 16 + lr) * KP + kk + kg * 8];
        #pragma unroll
        for (int mi = 0; mi < 4; ++mi)
            #pragma unroll
            for (int ni = 0; ni < 4; ++ni)
                acc[mi][ni] = __builtin_amdgcn_mfma_f32_16x16x32_bf16(
                    af[mi], bv[ni], acc[mi][ni], 0, 0, 0);
    }

    // epilogue: C/D layout col=lane&15, row=(lane>>4)*4+j  [m89-verified]
    const int rowoff = (lane >> 4) * 4;
    #pragma unroll
    for (int mi = 0; mi < 4; ++mi) {
        #pragma unroll
        for (int j = 0; j < 4; ++j) {
            int grow = m0 + wm + mi * 16 + rowoff + j;
            if (grow < M) {
                #pragma unroll
                for (int ni = 0; ni < 4; ++ni) {
                    int col = wn + ni * 16 + lr;
                    Mout[grow * (RREL * 128) + r * 128 + col] = f2bf(acc[mi][ni][j]);
                }
            }
        }
    }
}

// ---------------------------------------------------------------------------
// Gather: block per dst node, wave w handles relation w.
// acc = sum over ELL edges of Mt[src][r*128 + col] (bf16x2 per lane),
// * norm(deg), cross-wave LDS reduce, + sum_r bias[r], write out.
// ---------------------------------------------------------------------------
template<bool OUT_F32>
__global__ __launch_bounds__(256) void gather_kernel(
    const unsigned short* __restrict__ Mt,   // [n_src_side][R*128] bf16
    const int* __restrict__ ell, const int* __restrict__ cnt,
    const float* __restrict__ bias,          // [R][128]
    void* __restrict__ outp, int ndst)
{
    __shared__ float red[RREL][128];
    const int node = blockIdx.x;
    const int lane = threadIdx.x & 63;
    const int r    = threadIdx.x >> 6;
    const int idx  = r * ndst + node;
    const int c    = cnt[idx];
    const int deg  = c < CAP ? c : CAP;
    const int base = idx * CAP;
    const int coff = r * 128 + lane * 2;

    float ax = 0.f, ay = 0.f;
    int e = 0;
    for (; e + 4 <= deg; e += 4) {                 // 4 independent loads in flight
        int4 ss = *(const int4*)&ell[base + e];
        unsigned int v0 = *(const unsigned int*)&Mt[ss.x * 512 + coff];
        unsigned int v1 = *(const unsigned int*)&Mt[ss.y * 512 + coff];
        unsigned int v2 = *(const unsigned int*)&Mt[ss.z * 512 + coff];
        unsigned int v3 = *(const unsigned int*)&Mt[ss.w * 512 + coff];
        ax += __uint_as_float(v0 << 16) + __uint_as_float(v1 << 16)
            + __uint_as_float(v2 << 16) + __uint_as_float(v3 << 16);
        ay += __uint_as_float(v0 & 0xFFFF0000u) + __uint_as_float(v1 & 0xFFFF0000u)
            + __uint_as_float(v2 & 0xFFFF0000u) + __uint_as_float(v3 & 0xFFFF0000u);
    }
    for (; e < deg; ++e) {
        int s = ell[base + e];
        unsigned int v = *(const unsigned int*)&Mt[s * 512 + coff];
        ax += __uint_as_float(v << 16);
        ay += __uint_as_float(v & 0xFFFF0000u);
    }
    float norm = c > 0 ? 1.0f / (float)c : 0.0f;
    red[r][lane * 2]     = ax * norm;
    red[r][lane * 2 + 1] = ay * norm;
    __syncthreads();

    const int t = threadIdx.x;
    if (t < 128) {
        float s = red[0][t] + red[1][t] + red[2][t] + red[3][t]
                + bias[t] + bias[128 + t] + bias[256 + t] + bias[384 + t];
        if (OUT_F32) ((float*)outp)[node * 128 + t] = s;
        else ((unsigned short*)outp)[node * 128 + t] = f2bf(s);
    }
}

// ---------------------------------------------------------------------------
extern "C" void kernel_launch(void* const* d_in, const int* in_sizes, int n_in,
                              void* d_out, int out_size, void* d_ws, size_t ws_size,
                              hipStream_t stream)
{
    const float* x  = (const float*)d_in[0];
    const float* W1 = (const float*)d_in[1];
    const float* b1 = (const float*)d_in[2];
    const float* W2 = (const float*)d_in[3];
    const float* b2 = (const float*)d_in[4];
    const int* src1 = (const int*)d_in[5];
    const int* dst1 = (const int*)d_in[6];
    const int* src2 = (const int*)d_in[7];
    const int* dst2 = (const int*)d_in[8];

    char* p = (char*)d_ws;
    auto alloc = [&](size_t bytes) {
        char* q = p; p += (bytes + 255) & ~(size_t)255; return q;
    };
    unsigned short* m1   = (unsigned short*)alloc((size_t)N_SRC * 512 * 2);  // 204.8 MB
    int*            ell1 = (int*)alloc((size_t)RREL * N_MIDN * CAP * 4);     //  61.4 MB
    int*            cnt1 = (int*)alloc((size_t)RREL * N_MIDN * 4);
    unsigned short* h    = (unsigned short*)alloc((size_t)N_MIDN * 128 * 2);
    unsigned short* m2   = (unsigned short*)alloc((size_t)N_MIDN * 512 * 2); //  41.0 MB
    int*            ell2 = (int*)alloc((size_t)RREL * N_DSTN * CAP * 4);     //  12.3 MB
    int*            cnt2 = (int*)alloc((size_t)RREL * N_DSTN * 4);
    // total ~330.5 MB of ws

    hipMemsetAsync(cnt1, 0, (size_t)RREL * N_MIDN * 4, stream);
    hipMemsetAsync(cnt2, 0, (size_t)RREL * N_DSTN * 4, stream);

    fill_kernel<<<(RREL * E1N + 255) / 256, 256, 0, stream>>>(src1, dst1, cnt1, ell1, E1N, N_MIDN);
    fill_kernel<<<(RREL * E2N + 255) / 256, 256, 0, stream>>>(src2, dst2, cnt2, ell2, E2N, N_DSTN);

    gemm_kernel<256, false><<<dim3(RREL, (N_SRC + 127) / 128), 256, 0, stream>>>(x, W1, m1, N_SRC);
    gather_kernel<false><<<N_MIDN, 256, 0, stream>>>(m1, ell1, cnt1, b1, (void*)h, N_MIDN);
    gemm_kernel<128, true><<<dim3(RREL, (N_MIDN + 127) / 128), 256, 0, stream>>>(h, W2, m2, N_MIDN);
    gather_kernel<true><<<N_DSTN, 256, 0, stream>>>(m2, ell2, cnt2, b2, d_out, N_DSTN);
}

// Round 2
// 842.520 us; speedup vs baseline: 1.4696x; 1.4696x over previous
//
#include <hip/hip_runtime.h>
#include <hip/hip_bf16.h>

#define N_SRC  200000
#define N_MIDN 40000
#define N_DSTN 8000
#define RREL   4
#define E1N    1000000
#define E2N    200000
#define CAP    96   // ELL capacity; mean degree 25, P(overflow) ~ 1e-18

typedef __attribute__((ext_vector_type(8))) short bf16x8;
typedef __attribute__((ext_vector_type(4))) float f32x4;
typedef __attribute__((ext_vector_type(4))) unsigned short u16x4;

__device__ __forceinline__ unsigned short f2bf(float f) {
    unsigned int u = __float_as_uint(f);
    u = (u + 0x7FFFu + ((u >> 16) & 1u)) >> 16;   // RNE
    return (unsigned short)u;
}

__device__ __forceinline__ void gload_lds16(const void* g, void* l) {
    __builtin_amdgcn_global_load_lds((const __attribute__((address_space(1))) void*)g,
                                     (__attribute__((address_space(3))) void*)l, 16, 0, 0);
}

// ---------------------------------------------------------------------------
// ELL build: per edge, slot = atomicAdd(cnt[r][dst]); ell[r][dst][slot] = src
// ---------------------------------------------------------------------------
__global__ __launch_bounds__(256) void fill_kernel(
    const int* __restrict__ src, const int* __restrict__ dst,
    int* __restrict__ cnt, int* __restrict__ ell,
    int epr, int ndst)
{
    int i = blockIdx.x * 256 + threadIdx.x;
    if (i >= RREL * epr) return;
    int r = i / epr;
    int s = src[i];
    int d = dst[i];
    int node = r * ndst + d;
    int slot = atomicAdd(&cnt[node], 1);
    if (slot < CAP) ell[node * CAP + slot] = s;
}

// ---------------------------------------------------------------------------
// x (fp32 [N][256]) -> xb (bf16, per-row 16B-chunk XOR-swizzled: c ^= row&7)
// one thread per 8-element chunk
// ---------------------------------------------------------------------------
__global__ __launch_bounds__(256) void convx_kernel(
    const float* __restrict__ x, unsigned short* __restrict__ xb)
{
    int id  = blockIdx.x * 256 + threadIdx.x;
    int row = id >> 5;
    int c   = id & 31;
    const float4* xp = (const float4*)(x + ((size_t)row << 8) + (c << 3));
    float4 a = xp[0], b = xp[1];
    u16x4 o0, o1;
    o0.x = f2bf(a.x); o0.y = f2bf(a.y); o0.z = f2bf(a.z); o0.w = f2bf(a.w);
    o1.x = f2bf(b.x); o1.y = f2bf(b.y); o1.z = f2bf(b.z); o1.w = f2bf(b.w);
    int cs = c ^ (row & 7);
    u16x4* op = (u16x4*)(xb + ((size_t)row << 8) + (cs << 3));
    op[0] = o0; op[1] = o1;
}

// ---------------------------------------------------------------------------
// W [R][K][128] fp32 -> Wt [R*128][K] bf16 (transposed, k-contiguous)
// ---------------------------------------------------------------------------
template<int K>
__global__ __launch_bounds__(256) void convw_kernel(
    const float* __restrict__ W, unsigned short* __restrict__ Wt)
{
    int id = blockIdx.x * 256 + threadIdx.x;
    if (id >= RREL * K * 128) return;
    int n  = id & 127;
    int rk = id >> 7;            // r*K + k
    int k  = rk & (K - 1);
    int r  = rk / K;
    Wt[(size_t)(r * 128 + n) * K + k] = f2bf(W[id]);
}

// ---------------------------------------------------------------------------
// GEMM: Ab (bf16 swizzled [Mpad][K]) x Wt[r] ([128][K] bf16) -> Mout bf16 [M][512]
// block 256 = 4 waves, tile 128x128, full K in LDS (A only), B from global (L2)
// A staged via global_load_lds (linear copy; source is pre-swizzled)
// ---------------------------------------------------------------------------
template<int K>
__global__ __launch_bounds__(256, (K == 128) ? 4 : 2) void gemm_kernel(
    const unsigned short* __restrict__ Ab,
    const unsigned short* __restrict__ Wt,
    unsigned short* __restrict__ Mout, int M)
{
    __shared__ unsigned short As[128 * K];

    const int r    = blockIdx.x;
    const int m0   = blockIdx.y * 128;
    const int tid  = threadIdx.x;
    const int lane = tid & 63;
    const int wave = tid >> 6;

    // async linear copy: 128 rows x K*2 bytes, 4 KB per round (256 lanes x 16 B)
    const char* gp = (const char*)Ab + (size_t)m0 * (K * 2) + wave * 1024 + lane * 16;
    char* lp = (char*)As + wave * 1024;
    #pragma unroll
    for (int j = 0; j < K / 16; ++j)
        gload_lds16(gp + j * 4096, lp + j * 4096);
    __syncthreads();

    const int wm   = (wave & 1) * 64;
    const int wn   = (wave >> 1) * 64;
    const int lr   = lane & 15;
    const int kg   = lane >> 4;
    const int xorv = (lr & 7) << 4;           // row&7 == lr&7 for all fragment rows
    const unsigned short* Wr = Wt + (size_t)(r * 128) * K;
    const char* Asb = (const char*)As;

    f32x4 acc[4][4] = {};
    #pragma unroll 2
    for (int kk = 0; kk < K; kk += 32) {
        bf16x8 af[4], bv[4];
        const int kb = (kk * 2 + kg * 16) ^ xorv;
        #pragma unroll
        for (int mi = 0; mi < 4; ++mi)
            af[mi] = *(const bf16x8*)(Asb + (wm + mi * 16 + lr) * (K * 2) + kb);
        #pragma unroll
        for (int ni = 0; ni < 4; ++ni)
            bv[ni] = *(const bf16x8*)&Wr[(size_t)(wn + ni * 16 + lr) * K + kk + kg * 8];
        #pragma unroll
        for (int mi = 0; mi < 4; ++mi)
            #pragma unroll
            for (int ni = 0; ni < 4; ++ni)
                acc[mi][ni] = __builtin_amdgcn_mfma_f32_16x16x32_bf16(
                    af[mi], bv[ni], acc[mi][ni], 0, 0, 0);
    }

    // epilogue: C/D layout col=lane&15, row=(lane>>4)*4+j
    const int rowoff = (lane >> 4) * 4;
    #pragma unroll
    for (int mi = 0; mi < 4; ++mi) {
        #pragma unroll
        for (int j = 0; j < 4; ++j) {
            int grow = m0 + wm + mi * 16 + rowoff + j;
            if (grow < M) {
                #pragma unroll
                for (int ni = 0; ni < 4; ++ni)
                    Mout[(size_t)grow * 512 + r * 128 + wn + ni * 16 + lr]
                        = f2bf(acc[mi][ni][j]);
            }
        }
    }
}

// ---------------------------------------------------------------------------
// Gather: block per dst node, wave w handles relation w.
// OUT_F32=false -> write bf16 h in the row-swizzled layout gemm2 stages from.
// ---------------------------------------------------------------------------
template<bool OUT_F32>
__global__ __launch_bounds__(256) void gather_kernel(
    const unsigned short* __restrict__ Mt,   // [n_src_side][512] bf16
    const int* __restrict__ ell, const int* __restrict__ cnt,
    const float* __restrict__ bias,          // [R][128]
    void* __restrict__ outp, int ndst)
{
    __shared__ float red[RREL][128];
    const int node = blockIdx.x;
    const int lane = threadIdx.x & 63;
    const int r    = threadIdx.x >> 6;
    const int idx  = r * ndst + node;
    const int c    = cnt[idx];
    const int deg  = c < CAP ? c : CAP;
    const int base = idx * CAP;
    const int coff = r * 128 + lane * 2;

    float ax = 0.f, ay = 0.f;
    int e = 0;
    for (; e + 4 <= deg; e += 4) {
        int4 ss = *(const int4*)&ell[base + e];
        unsigned int v0 = *(const unsigned int*)&Mt[(size_t)ss.x * 512 + coff];
        unsigned int v1 = *(const unsigned int*)&Mt[(size_t)ss.y * 512 + coff];
        unsigned int v2 = *(const unsigned int*)&Mt[(size_t)ss.z * 512 + coff];
        unsigned int v3 = *(const unsigned int*)&Mt[(size_t)ss.w * 512 + coff];
        ax += __uint_as_float(v0 << 16) + __uint_as_float(v1 << 16)
            + __uint_as_float(v2 << 16) + __uint_as_float(v3 << 16);
        ay += __uint_as_float(v0 & 0xFFFF0000u) + __uint_as_float(v1 & 0xFFFF0000u)
            + __uint_as_float(v2 & 0xFFFF0000u) + __uint_as_float(v3 & 0xFFFF0000u);
    }
    for (; e < deg; ++e) {
        int s = ell[base + e];
        unsigned int v = *(const unsigned int*)&Mt[(size_t)s * 512 + coff];
        ax += __uint_as_float(v << 16);
        ay += __uint_as_float(v & 0xFFFF0000u);
    }
    float norm = c > 0 ? 1.0f / (float)c : 0.0f;
    red[r][lane * 2]     = ax * norm;
    red[r][lane * 2 + 1] = ay * norm;
    __syncthreads();

    const int t = threadIdx.x;
    if (t < 128) {
        float s = red[0][t] + red[1][t] + red[2][t] + red[3][t]
                + bias[t] + bias[128 + t] + bias[256 + t] + bias[384 + t];
        if constexpr (OUT_F32) {
            ((float*)outp)[node * 128 + t] = s;
        } else {
            int cs = ((t >> 3) ^ (node & 7)) << 3;           // swizzled h layout
            ((unsigned short*)outp)[node * 128 + cs + (t & 7)] = f2bf(s);
        }
    }
}

// ---------------------------------------------------------------------------
extern "C" void kernel_launch(void* const* d_in, const int* in_sizes, int n_in,
                              void* d_out, int out_size, void* d_ws, size_t ws_size,
                              hipStream_t stream)
{
    const float* x  = (const float*)d_in[0];
    const float* W1 = (const float*)d_in[1];
    const float* b1 = (const float*)d_in[2];
    const float* W2 = (const float*)d_in[3];
    const float* b2 = (const float*)d_in[4];
    const int* src1 = (const int*)d_in[5];
    const int* dst1 = (const int*)d_in[6];
    const int* src2 = (const int*)d_in[7];
    const int* dst2 = (const int*)d_in[8];

    char* p = (char*)d_ws;
    auto alloc = [&](size_t bytes) {
        char* q = p; p += (bytes + 255) & ~(size_t)255; return q;
    };
    unsigned short* xb   = (unsigned short*)alloc((size_t)(N_SRC + 64) * 256 * 2);  // 102.4 MB
    unsigned short* m1   = (unsigned short*)alloc((size_t)N_SRC * 512 * 2);         // 204.8 MB
    int*            ell1 = (int*)alloc((size_t)RREL * N_MIDN * CAP * 4);            //  61.4 MB
    int*            cnt1 = (int*)alloc((size_t)RREL * N_MIDN * 4);
    unsigned short* h    = (unsigned short*)alloc((size_t)(N_MIDN + 64) * 128 * 2); //  10.3 MB
    unsigned short* wt1  = (unsigned short*)alloc((size_t)RREL * 128 * 256 * 2);
    unsigned short* wt2  = (unsigned short*)alloc((size_t)RREL * 128 * 128 * 2);
    // ~380 MB high-water. Layer-2 scratch aliases xb (xb dead after gemm1):
    char* q2 = (char*)xb;
    unsigned short* m2   = (unsigned short*)q2; q2 += (size_t)N_MIDN * 512 * 2;     //  41.0 MB
    int*            ell2 = (int*)q2;            q2 += (size_t)RREL * N_DSTN * CAP * 4;
    int*            cnt2 = (int*)q2;

    hipMemsetAsync(cnt1, 0, (size_t)RREL * N_MIDN * 4, stream);
    convw_kernel<256><<<512, 256, 0, stream>>>(W1, wt1);
    convw_kernel<128><<<256, 256, 0, stream>>>(W2, wt2);
    convx_kernel<<<(N_SRC * 32) / 256, 256, 0, stream>>>(x, xb);
    fill_kernel<<<(RREL * E1N + 255) / 256, 256, 0, stream>>>(src1, dst1, cnt1, ell1, E1N, N_MIDN);

    gemm_kernel<256><<<dim3(RREL, (N_SRC + 127) / 128), 256, 0, stream>>>(xb, wt1, m1, N_SRC);
    gather_kernel<false><<<N_MIDN, 256, 0, stream>>>(m1, ell1, cnt1, b1, (void*)h, N_MIDN);

    // layer-2 ELL build only now (ell2/cnt2 alias xb, which gemm1 read)
    hipMemsetAsync(cnt2, 0, (size_t)RREL * N_DSTN * 4, stream);
    fill_kernel<<<(RREL * E2N + 255) / 256, 256, 0, stream>>>(src2, dst2, cnt2, ell2, E2N, N_DSTN);

    gemm_kernel<128><<<dim3(RREL, (N_MIDN + 127) / 128), 256, 0, stream>>>(h, wt2, m2, N_MIDN);
    gather_kernel<true><<<N_DSTN, 256, 0, stream>>>(m2, ell2, cnt2, b2, d_out, N_DSTN);
}